// Round 1
// baseline (105.018 us; speedup 1.0000x reference)
//
#include <hip/hip_runtime.h>
#include <hip/hip_bf16.h>

typedef __attribute__((ext_vector_type(8))) short short8;
typedef __attribute__((ext_vector_type(4))) float f32x4;

namespace {
constexpr int Hc  = 8;
constexpr int Nc  = 2048;   // N (rows per Q or K)
constexpr int NXc = 4096;   // 2N
constexpr int Pc  = 64;
constexpr int Mc  = 4;
constexpr int Dc  = 256;
constexpr int TN  = 128;    // n rows per block
constexpr int LDX = 72;     // padded LDS row (bf16 elems): 64 + 8 -> 2-way bank aliasing only (free)
constexpr int DCk = 64;     // d-chunk
}

__device__ inline unsigned int bfpack(float a, float b) {
  union { __hip_bfloat162 h; unsigned int u; } cv;
  cv.h = __float22bfloat162_rn(make_float2(a, b));
  return cv.u;
}

__global__ __launch_bounds__(256, 2) void sketch_kernel(
    const float* __restrict__ Q, const float* __restrict__ K,
    const int* __restrict__ SK, const float* __restrict__ SGN,
    float* __restrict__ OUT)
{
  __shared__ __hip_bfloat16 Xs[TN][LDX];   // 18432 B
  __shared__ __hip_bfloat16 Ws[DCk][LDX];  //  9216 B
  __shared__ float Ss[Mc * Dc];            //  4096 B

  const int t    = threadIdx.x;
  const int lane = t & 63;
  const int wv   = t >> 6;       // wave 0..3, owns n rows [wv*32, wv*32+32)
  const int bh   = blockIdx.y;   // 0..15
  const int b    = bh >> 3;
  const int n0   = blockIdx.x * TN;

  // stage sign table (1024 floats)
  for (int i = t; i < Mc * Dc; i += 256) Ss[i] = SGN[i];

  // stage X tile: 128 rows x 64 fp32 -> bf16 LDS. 4 threads/row, 16 floats each.
  {
    const int q  = t & 3;
    const int r0 = t >> 2;
    for (int half = 0; half < 2; ++half) {
      const int r = r0 + half * 64;
      const int n = n0 + r;
      const float* src = (n < Nc) ? (Q + ((size_t)bh * Nc + n) * Pc)
                                  : (K + ((size_t)bh * Nc + (n - Nc)) * Pc);
      const f32x4* s4 = (const f32x4*)(src + q * 16);
      f32x4 f0 = s4[0], f1 = s4[1], f2 = s4[2], f3 = s4[3];
      uint4 u, v;
      u.x = bfpack(f0.x, f0.y); u.y = bfpack(f0.z, f0.w);
      u.z = bfpack(f1.x, f1.y); u.w = bfpack(f1.z, f1.w);
      v.x = bfpack(f2.x, f2.y); v.y = bfpack(f2.z, f2.w);
      v.z = bfpack(f3.x, f3.y); v.w = bfpack(f3.z, f3.w);
      *(uint4*)&Xs[r][q * 16]     = u;
      *(uint4*)&Xs[r][q * 16 + 8] = v;
    }
  }

  __syncthreads();

  // A fragments: lane holds A[row=lane&15][k=(lane>>4)*8 + j]  (verified m89/m91)
  short8 afr[2][2];
  const int acol = (lane >> 4) * 8;
  {
    const int arow = wv * 32 + (lane & 15);
    for (int ti = 0; ti < 2; ++ti)
      for (int ks = 0; ks < 2; ++ks)
        afr[ti][ks] = *(const short8*)&Xs[arow + ti * 16][ks * 32 + acol];
  }

  for (int dc = 0; dc < 4; ++dc) {
    f32x4 AS[2][4];
    for (int ti = 0; ti < 2; ++ti)
      for (int tj = 0; tj < 4; ++tj)
        AS[ti][tj] = (f32x4){0.f, 0.f, 0.f, 0.f};

    for (int m = 0; m < Mc; ++m) {
      __syncthreads();  // previous phase's Ws readers done
      // gather 64 sketch rows for (m, d-chunk): row d = dc*64 + r, src row idx = SK[b,m,d]
      {
        const int q = t & 3;
        const int r = t >> 2;
        const int d = dc * 64 + r;
        const int idx = SK[b * (Mc * Dc) + m * Dc + d];
        const float* src = (idx < Nc) ? (Q + ((size_t)bh * Nc + idx) * Pc)
                                      : (K + ((size_t)bh * Nc + (idx - Nc)) * Pc);
        const f32x4* s4 = (const f32x4*)(src + q * 16);
        f32x4 f0 = s4[0], f1 = s4[1], f2 = s4[2], f3 = s4[3];
        uint4 u, v;
        u.x = bfpack(f0.x, f0.y); u.y = bfpack(f0.z, f0.w);
        u.z = bfpack(f1.x, f1.y); u.w = bfpack(f1.z, f1.w);
        v.x = bfpack(f2.x, f2.y); v.y = bfpack(f2.z, f2.w);
        v.z = bfpack(f3.x, f3.y); v.w = bfpack(f3.z, f3.w);
        *(uint4*)&Ws[r][q * 16]     = u;
        *(uint4*)&Ws[r][q * 16 + 8] = v;
      }
      __syncthreads();

      // B fragments: lane holds B[k=(lane>>4)*8+j][col=lane&15] = Ws[col][k]
      short8 bfr[4][2];
      const int brow = lane & 15;
      for (int tj = 0; tj < 4; ++tj)
        for (int ks = 0; ks < 2; ++ks)
          bfr[tj][ks] = *(const short8*)&Ws[tj * 16 + brow][ks * 32 + acol];

      // product tiles + fused epilogue; C layout: col=lane&15, row=(lane>>4)*4+reg
      for (int ti = 0; ti < 2; ++ti)
        for (int tj = 0; tj < 4; ++tj) {
          f32x4 c = {0.f, 0.f, 0.f, 0.f};
          c = __builtin_amdgcn_mfma_f32_16x16x32_bf16(afr[ti][0], bfr[tj][0], c, 0, 0, 0);
          c = __builtin_amdgcn_mfma_f32_16x16x32_bf16(afr[ti][1], bfr[tj][1], c, 0, 0, 0);
          const float sg = Ss[m * Dc + dc * 64 + tj * 16 + (lane & 15)];
          AS[ti][tj].x += sg * __expf(c.x);
          AS[ti][tj].y += sg * __expf(c.y);
          AS[ti][tj].z += sg * __expf(c.z);
          AS[ti][tj].w += sg * __expf(c.w);
        }
    }

    // store this d-chunk: n = n0 + wv*32 + ti*16 + (lane>>4)*4 + r ; d = dc*64 + tj*16 + (lane&15)
    const int dbase = dc * 64 + (lane & 15);
    const int nb    = n0 + wv * 32 + ((lane >> 4) << 2);
    for (int ti = 0; ti < 2; ++ti)
      for (int tj = 0; tj < 4; ++tj) {
        const size_t base = ((size_t)bh * NXc + (nb + ti * 16)) * Dc + dbase + tj * 16;
        OUT[base + 0 * (size_t)Dc] = AS[ti][tj].x;
        OUT[base + 1 * (size_t)Dc] = AS[ti][tj].y;
        OUT[base + 2 * (size_t)Dc] = AS[ti][tj].z;
        OUT[base + 3 * (size_t)Dc] = AS[ti][tj].w;
      }
  }
}

extern "C" void kernel_launch(void* const* d_in, const int* in_sizes, int n_in,
                              void* d_out, int out_size, void* d_ws, size_t ws_size,
                              hipStream_t stream) {
  (void)in_sizes; (void)n_in; (void)out_size; (void)d_ws; (void)ws_size;
  const float* Q   = (const float*)d_in[0];
  const float* K   = (const float*)d_in[1];
  const int*   SK  = (const int*)d_in[2];
  const float* SGN = (const float*)d_in[3];
  float* OUT = (float*)d_out;

  dim3 grid(NXc / TN, 16);   // 32 n-tiles x 16 (b,h)
  dim3 block(256);
  sketch_kernel<<<grid, block, 0, stream>>>(Q, K, SK, SGN, OUT);
}

// Round 2
// 102.335 us; speedup vs baseline: 1.0262x; 1.0262x over previous
//
#include <hip/hip_runtime.h>
#include <hip/hip_bf16.h>

typedef __attribute__((ext_vector_type(8))) short short8;
typedef __attribute__((ext_vector_type(4))) float f32x4;

namespace {
constexpr int Nc  = 2048;   // N
constexpr int NXc = 4096;   // 2N
constexpr int Pc  = 64;
constexpr int Mc  = 4;
constexpr int Dc  = 256;
constexpr int BH  = 16;
constexpr int LDW = 72;     // padded LDS row stride (bf16): 64+8
constexpr float LOG2E = 1.4426950408889634f;
}

__device__ inline float fexp2(float x) {
#if __has_builtin(__builtin_amdgcn_exp2f)
  return __builtin_amdgcn_exp2f(x);
#else
  return exp2f(x);
#endif
}

__device__ inline unsigned int bfpack(float a, float b) {
  union { __hip_bfloat162 h; unsigned int u; } cv;
  cv.h = __float22bfloat162_rn(make_float2(a, b));
  return cv.u;
}

// Pre-pass: convert X (Q||K) -> bf16 Xb [16][4096][64]; gather sketch rows ->
// bf16 Wb [16][1024][64], pre-scaled by log2(e). 8 threads per 64-elem row.
__global__ __launch_bounds__(256) void prepass_kernel(
    const float* __restrict__ Q, const float* __restrict__ K,
    const int* __restrict__ SK,
    __hip_bfloat16* __restrict__ Xb, __hip_bfloat16* __restrict__ Wb)
{
  const int t = blockIdx.x * 256 + threadIdx.x;
  const int q = t & 7;          // 8-float octant
  const int r = t >> 3;         // row id in [0, 81920)
  const int NXROWS = BH * NXc;  // 65536

  const float* src;
  __hip_bfloat16* dst;
  float scale;
  if (r < NXROWS) {
    const int bh = r >> 12, n = r & (NXc - 1);
    src = (n < Nc) ? (Q + ((size_t)bh * Nc + n) * Pc)
                   : (K + ((size_t)bh * Nc + (n - Nc)) * Pc);
    dst = Xb + (size_t)r * Pc;
    scale = 1.0f;
  } else {
    const int j  = r - NXROWS;            // [0, 16384)
    const int bh = j >> 10;
    const int md = j & 1023;
    const int b  = bh >> 3;
    const int idx = SK[b * (Mc * Dc) + md];
    src = (idx < Nc) ? (Q + ((size_t)bh * Nc + idx) * Pc)
                     : (K + ((size_t)bh * Nc + (idx - Nc)) * Pc);
    dst = Wb + (size_t)j * Pc;
    scale = LOG2E;
  }
  const f32x4* s4 = (const f32x4*)(src + q * 8);
  f32x4 f0 = s4[0], f1 = s4[1];
  uint4 u;
  u.x = bfpack(f0.x * scale, f0.y * scale);
  u.y = bfpack(f0.z * scale, f0.w * scale);
  u.z = bfpack(f1.x * scale, f1.y * scale);
  u.w = bfpack(f1.z * scale, f1.w * scale);
  *(uint4*)(dst + q * 8) = u;
}

// Main: per block (64 n-rows, one bh). A frags straight from global; W streamed
// through double-buffered padded LDS, one barrier per phase, prefetch overlapped.
__global__ __launch_bounds__(256, 4) void sketch_main(
    const __hip_bfloat16* __restrict__ Xb, const __hip_bfloat16* __restrict__ Wb,
    const float* __restrict__ SGN, float* __restrict__ OUT)
{
  __shared__ __hip_bfloat16 Ws[2][64][LDW];  // 18432 B
  __shared__ float Ss[Mc * Dc];              //  4096 B

  const int t    = threadIdx.x;
  const int lane = t & 63;
  const int wv   = t >> 6;
  const int bh   = blockIdx.y;
  const int n0   = blockIdx.x * 64;

  for (int i = t; i < Mc * Dc; i += 256) Ss[i] = SGN[i];

  // A fragments direct from global: lane holds A[row=lane&15][k=quad*8+j]
  const int brow = lane & 15;
  const int acol = (lane >> 4) * 8;
  short8 afr[2];
  {
    const __hip_bfloat16* ap =
        Xb + ((size_t)bh * NXc + n0 + wv * 16 + brow) * Pc + acol;
    afr[0] = *(const short8*)ap;
    afr[1] = *(const short8*)(ap + 32);
  }

  const __hip_bfloat16* wbase = Wb + (size_t)bh * (Mc * Dc) * Pc;
  const int tr = t >> 2;        // staging row 0..63
  const int tq = t & 3;         // 16-elem quarter

  // phase p: dc=p>>2, m=p&3; W chunk row base:
  auto crow = [](int p) { return (p & 3) * Dc + (p >> 2) * 64; };

  // preload chunk 0 into buf 0
  {
    const __hip_bfloat16* wp = wbase + (size_t)(crow(0) + tr) * Pc + tq * 16;
    uint4 wa = *(const uint4*)wp;
    uint4 wb = *(const uint4*)(wp + 8);
    *(uint4*)&Ws[0][tr][tq * 16]     = wa;
    *(uint4*)&Ws[0][tr][tq * 16 + 8] = wb;
  }
  __syncthreads();

  f32x4 AS[4];
  for (int tj = 0; tj < 4; ++tj) AS[tj] = (f32x4){0.f, 0.f, 0.f, 0.f};

  for (int p = 0; p < 16; ++p) {
    // issue next chunk's global loads early (overlap with compute)
    const int pn = (p < 15) ? p + 1 : 15;
    const __hip_bfloat16* wp = wbase + (size_t)(crow(pn) + tr) * Pc + tq * 16;
    uint4 wa = *(const uint4*)wp;
    uint4 wb = *(const uint4*)(wp + 8);

    // compute from Ws[p&1]
    const int buf = p & 1;
    short8 bfr[4][2];
    for (int tj = 0; tj < 4; ++tj) {
      bfr[tj][0] = *(const short8*)&Ws[buf][tj * 16 + brow][acol];
      bfr[tj][1] = *(const short8*)&Ws[buf][tj * 16 + brow][32 + acol];
    }
    const int m  = p & 3;
    const int dc = p >> 2;
    for (int tj = 0; tj < 4; ++tj) {
      f32x4 c = {0.f, 0.f, 0.f, 0.f};
      c = __builtin_amdgcn_mfma_f32_16x16x32_bf16(afr[0], bfr[tj][0], c, 0, 0, 0);
      c = __builtin_amdgcn_mfma_f32_16x16x32_bf16(afr[1], bfr[tj][1], c, 0, 0, 0);
      const float sg = Ss[m * Dc + dc * 64 + tj * 16 + brow];
      AS[tj].x = fmaf(sg, fexp2(c.x), AS[tj].x);
      AS[tj].y = fmaf(sg, fexp2(c.y), AS[tj].y);
      AS[tj].z = fmaf(sg, fexp2(c.z), AS[tj].z);
      AS[tj].w = fmaf(sg, fexp2(c.w), AS[tj].w);
    }

    if (m == 3) {
      // store dc chunk: n = n0+wv*16+quad*4+reg, d = dc*64+tj*16+brow
      const int nb    = n0 + wv * 16 + ((lane >> 4) << 2);
      const int dbase = dc * 64 + brow;
      for (int tj = 0; tj < 4; ++tj) {
        const size_t base = ((size_t)bh * NXc + nb) * Dc + dbase + tj * 16;
        OUT[base + 0 * (size_t)Dc] = AS[tj].x;
        OUT[base + 1 * (size_t)Dc] = AS[tj].y;
        OUT[base + 2 * (size_t)Dc] = AS[tj].z;
        OUT[base + 3 * (size_t)Dc] = AS[tj].w;
        AS[tj] = (f32x4){0.f, 0.f, 0.f, 0.f};
      }
    }

    // stage next chunk into the other buffer
    *(uint4*)&Ws[buf ^ 1][tr][tq * 16]     = wa;
    *(uint4*)&Ws[buf ^ 1][tr][tq * 16 + 8] = wb;
    __syncthreads();
  }
}

extern "C" void kernel_launch(void* const* d_in, const int* in_sizes, int n_in,
                              void* d_out, int out_size, void* d_ws, size_t ws_size,
                              hipStream_t stream) {
  (void)in_sizes; (void)n_in; (void)out_size; (void)ws_size;
  const float* Q   = (const float*)d_in[0];
  const float* K   = (const float*)d_in[1];
  const int*   SK  = (const int*)d_in[2];
  const float* SGN = (const float*)d_in[3];
  float* OUT = (float*)d_out;

  __hip_bfloat16* Xb = (__hip_bfloat16*)d_ws;                       // 8 MiB
  __hip_bfloat16* Wb = (__hip_bfloat16*)((char*)d_ws + (size_t)BH * NXc * Pc * 2);  // 2 MiB

  prepass_kernel<<<dim3(2560), dim3(256), 0, stream>>>(Q, K, SK, Xb, Wb);
  sketch_main<<<dim3(NXc / 64, BH), dim3(256), 0, stream>>>(Xb, Wb, SGN, OUT);
}